// Round 10
// baseline (418.766 us; speedup 1.0000x reference)
//
#include <hip/hip_runtime.h>
#include <hip/hip_bf16.h>

#define Bdim 64
#define Tdim 96
#define Pdim 256
#define Hdim 128
#define Gdim 512   // 4*H
#define Odim 24
#define BH   32    // batches per block (one batch-half)

typedef _Float16 f16x8  __attribute__((ext_vector_type(8)));
typedef __fp16   fp16x2 __attribute__((ext_vector_type(2)));
typedef float    f32x16 __attribute__((ext_vector_type(16)));
typedef float    f32x2  __attribute__((ext_vector_type(2)));

union H8 { uint4 u4; unsigned int u[4]; unsigned short s[8]; _Float16 h[8]; f16x8 v; };
union HS { _Float16 h; unsigned short s; };
union PK2 { fp16x2 v; unsigned int u; };

__device__ __forceinline__ float exp2_fast(float x) {
#if __has_builtin(__builtin_amdgcn_exp2f)
    return __builtin_amdgcn_exp2f(x);
#else
    return __expf(x * 0.6931471805599453f);
#endif
}

#define MFMA __builtin_amdgcn_mfma_f32_32x32x16_f16

// R9: TWO INDEPENDENT BARRIER DOMAINS PER CU.
// Grid = 512 = (p, batch-half); 512 threads = 8 waves; launch_bounds(512,4)
// -> 2 blocks/CU with independent __syncthreads. Resource-contention coupling
// makes co-resident blocks anti-phase stable: one block's LDS-heavy gemm
// overlaps the other's VALU-heavy epilogue (R2-R8 showed wall = VALU+LDS+MFMA
// summed inside a single barrier domain, invariant to schedule).
//
// Each wave owns 64 r'-rows (2 MFMA tiles) sharing ONE B-fragment read
// -> per-CU LDS read traffic halves. One barrier per step (double-buffered h).
// Row permutation: row-local rr -> gate = rr&3, kk = 16w + 8m + 4*((rr>>2)&1)
// + (rr>>3), so a lane's 4 outputs are CONTIGUOUS in k -> epilogue store is
// 2x v_cvt_pkrtz + one ds_write_b64 per tile.
// gx (x*W_ih + bias) fused as 9th MFMA K-step; its A-frag is 2 packed f16 in
// ONE VGPR per tile (rest zeros). h: XOR-swizzled 16B chunks (chunk c of row b
// at pos c^(b&15)), f16. Weights prescaled by log2e (2log2e for g gate);
// scaled-domain cell state; paired-rcp epilogue (5 exp2 + 1 rcp per (b,k)).
__global__ __launch_bounds__(512, 4)
void lstm_fused(const float* __restrict__ x,
                const float* __restrict__ W_ih,
                const float* __restrict__ W_hh,
                const float* __restrict__ b_ih,
                const float* __restrict__ b_hh,
                const float* __restrict__ W_fc,
                const float* __restrict__ b_fc,
                float* __restrict__ out)
{
    __shared__ unsigned short hbuf[2][BH * Hdim];  // 16 KB, double-buffered, swizzled

    const int p    = blockIdx.x >> 1;
    const int half = blockIdx.x & 1;
    const int tid  = threadIdx.x;
    const int w    = tid >> 6;    // wave 0..7
    const int l31  = tid & 31;
    const int hi   = (tid >> 5) & 1;

    const float L1 = 1.4426950408889634f;  // log2(e)
    const float L2 = 2.0f * L1;

    for (int i = tid; i < 2 * BH * Hdim; i += 512) ((unsigned short*)hbuf)[i] = 0;

    // ---- preload A fragments: 2 tiles x 8 K-steps of W_hh + 1-VGPR gx pair ----
    f16x8 afr[2][8];
    unsigned int gxp[2];
    {
        const int gate = l31 & 3;
        const float sc = (gate == 2) ? L2 : L1;   // g gate: 2*log2e
        #pragma unroll
        for (int m = 0; m < 2; ++m) {
            const int kk   = 16 * w + 8 * m + 4 * ((l31 >> 2) & 1) + (l31 >> 3);
            const int orow = gate * 128 + kk;
            const float* rowp = W_hh + (size_t)p * Gdim * Hdim + (size_t)orow * Hdim;
            #pragma unroll
            for (int ks = 0; ks < 8; ++ks) {
                int k0 = ks * 16 + hi * 8;
                float4 va = *(const float4*)(rowp + k0);
                float4 vb = *(const float4*)(rowp + k0 + 4);
                H8 u;
                u.h[0] = (_Float16)(sc * va.x); u.h[1] = (_Float16)(sc * va.y);
                u.h[2] = (_Float16)(sc * va.z); u.h[3] = (_Float16)(sc * va.w);
                u.h[4] = (_Float16)(sc * vb.x); u.h[5] = (_Float16)(sc * vb.y);
                u.h[6] = (_Float16)(sc * vb.z); u.h[7] = (_Float16)(sc * vb.w);
                afr[m][ks] = u.v;
            }
            HS ga, gb;
            ga.h = (_Float16)(sc * W_ih[(size_t)p * Gdim + orow]);
            gb.h = (_Float16)(sc * (b_ih[(size_t)p * Gdim + orow] +
                                    b_hh[(size_t)p * Gdim + orow]));
            gxp[m] = hi ? 0u : ((unsigned int)ga.s | ((unsigned int)gb.s << 16));
        }
    }

    // swizzled read base: addr(ks) = rb0 ^ (ks<<5)   (chunk c = 2ks+hi)
    const int rb0 = (l31 << 8) | ((hi ^ (l31 & 15)) << 4);
    // write offsets (bytes): tile m -> chunk 2w+m of row l31, byte 8*hi within chunk
    const int wo0 = (l31 << 8) + (((2 * w + 0) ^ (l31 & 15)) << 4) + (hi << 3);
    const int wo1 = (l31 << 8) + (((2 * w + 1) ^ (l31 & 15)) << 4) + (hi << 3);

    f32x2 cre[4];   // scaled-domain cell state: [tile*2 + j], pair = (q=2j, q=2j+1)
    #pragma unroll
    for (int i = 0; i < 4; ++i) cre[i] = f32x2{0.f, 0.f};

    const float* xp = x + (size_t)((half * BH + l31) * Tdim) * Pdim + p;
    float xv = xp[0];

    __syncthreads();

    for (int t = 0; t < Tdim; ++t) {
        const unsigned short* rbuf = hbuf[t & 1];
        unsigned short* wbuf = hbuf[(t & 1) ^ 1];
        const char* rc = (const char*)rbuf;
        float xn = xp[(size_t)((t + 1 < Tdim) ? t + 1 : t) * Pdim];

        // gx operand frags (1 live dword each + shared zeros)
        PK2 xb; xb.v = __builtin_amdgcn_cvt_pkrtz(xv, 1.0f);
        H8 bg; bg.u[0] = hi ? 0u : xb.u; bg.u[1] = 0; bg.u[2] = 0; bg.u[3] = 0;
        H8 g0; g0.u[0] = gxp[0]; g0.u[1] = 0; g0.u[2] = 0; g0.u[3] = 0;
        H8 g1; g1.u[0] = gxp[1]; g1.u[1] = 0; g1.u[2] = 0; g1.u[3] = 0;

        // gemm: 4-ahead staged b128 reads, tiles interleaved, in-place acc
        f32x16 acc0, acc1;
        {
            H8 f0, f1, f2, f3, f4, f5, f6, f7;
            f0.u4 = *(const uint4*)(rc + (rb0 ^ (0 << 5)));
            f1.u4 = *(const uint4*)(rc + (rb0 ^ (1 << 5)));
            f2.u4 = *(const uint4*)(rc + (rb0 ^ (2 << 5)));
            f3.u4 = *(const uint4*)(rc + (rb0 ^ (3 << 5)));
            f32x16 z;
            #pragma unroll
            for (int j = 0; j < 16; ++j) z[j] = 0.f;
            acc0 = MFMA(afr[0][0], f0.v, z, 0, 0, 0);
            acc1 = MFMA(afr[1][0], f0.v, z, 0, 0, 0);
            f4.u4 = *(const uint4*)(rc + (rb0 ^ (4 << 5)));
            acc0 = MFMA(afr[0][1], f1.v, acc0, 0, 0, 0);
            acc1 = MFMA(afr[1][1], f1.v, acc1, 0, 0, 0);
            f5.u4 = *(const uint4*)(rc + (rb0 ^ (5 << 5)));
            acc0 = MFMA(afr[0][2], f2.v, acc0, 0, 0, 0);
            acc1 = MFMA(afr[1][2], f2.v, acc1, 0, 0, 0);
            f6.u4 = *(const uint4*)(rc + (rb0 ^ (6 << 5)));
            acc0 = MFMA(afr[0][3], f3.v, acc0, 0, 0, 0);
            acc1 = MFMA(afr[1][3], f3.v, acc1, 0, 0, 0);
            f7.u4 = *(const uint4*)(rc + (rb0 ^ (7 << 5)));
            acc0 = MFMA(afr[0][4], f4.v, acc0, 0, 0, 0);
            acc1 = MFMA(afr[1][4], f4.v, acc1, 0, 0, 0);
            acc0 = MFMA(afr[0][5], f5.v, acc0, 0, 0, 0);
            acc1 = MFMA(afr[1][5], f5.v, acc1, 0, 0, 0);
            acc0 = MFMA(afr[0][6], f6.v, acc0, 0, 0, 0);
            acc1 = MFMA(afr[1][6], f6.v, acc1, 0, 0, 0);
            acc0 = MFMA(afr[0][7], f7.v, acc0, 0, 0, 0);
            acc1 = MFMA(afr[1][7], f7.v, acc1, 0, 0, 0);
            acc0 = MFMA(g0.v, bg.v, acc0, 0, 0, 0);
            acc1 = MFMA(g1.v, bg.v, acc1, 0, 0, 0);
        }

        // epilogue, tile-sequential; one b64 write per tile (k-contiguous q0..q3)
        #pragma unroll
        for (int m = 0; m < 2; ++m) {
            const f32x16& a = m ? acc1 : acc0;
            f32x2 hv[2];
            #pragma unroll
            for (int j = 0; j < 2; ++j) {
                f32x2 yi = {a[8 * j + 0], a[8 * j + 4]};
                f32x2 yf = {a[8 * j + 1], a[8 * j + 5]};
                f32x2 yg = {a[8 * j + 2], a[8 * j + 6]};   // prescaled by 2*log2e
                f32x2 yo = {a[8 * j + 3], a[8 * j + 7]};
                f32x2 Ef = {exp2_fast(-yf.x), exp2_fast(-yf.y)};
                f32x2 Ei = {exp2_fast(-yi.x), exp2_fast(-yi.y)};
                f32x2 Eg = {exp2_fast(yg.x),  exp2_fast(yg.y)};
                f32x2 t1 = Ef + 1.0f;
                f32x2 t2 = Ei + 1.0f;
                f32x2 t3 = Eg + 1.0f;
                f32x2 t4 = Eg - 1.0f;
                f32x2 den = (t1 * t2) * t3;
                f32x2 num = (cre[m * 2 + j] * t2) * t3 + (L2 * t4) * t1;
                float D = den.x * den.y;
                float r = __builtin_amdgcn_rcpf(D);
                f32x2 inv = {r * den.y, r * den.x};
                f32x2 cn  = num * inv;
                cn.x = __builtin_amdgcn_fmed3f(cn.x, -30.0f, 30.0f);
                cn.y = __builtin_amdgcn_fmed3f(cn.y, -30.0f, 30.0f);
                cre[m * 2 + j] = cn;
                f32x2 Eo = {exp2_fast(-yo.x), exp2_fast(-yo.y)};
                f32x2 Ec = {exp2_fast(cn.x),  exp2_fast(cn.y)};
                f32x2 d2 = (Eo + 1.0f) * (Ec + 1.0f);
                float D2 = d2.x * d2.y;
                float r2 = __builtin_amdgcn_rcpf(D2);
                f32x2 j2 = {r2 * d2.y, r2 * d2.x};
                hv[j] = (Ec - 1.0f) * j2;
            }
            PK2 lo, hi2;
            lo.v  = __builtin_amdgcn_cvt_pkrtz(hv[0].x, hv[0].y);   // q0,q1
            hi2.v = __builtin_amdgcn_cvt_pkrtz(hv[1].x, hv[1].y);   // q2,q3
            uint2 valw = {lo.u, hi2.u};
            *(uint2*)((char*)wbuf + (m ? wo1 : wo0)) = valw;
        }

        __syncthreads();
        xv = xn;
    }
    // Tdim even -> final h in hbuf[0] (swizzled layout)

    // ---- FC: out[b][o][p] = sum_k W_fc[p][o][k]*h[b][k] + b_fc[p][o] ----
    const float* wfc = W_fc + (size_t)p * Odim * Hdim;
    const float* bfc = b_fc + (size_t)p * Odim;
    for (int i = tid; i < BH * Odim; i += 512) {
        int o = i % Odim;
        int b = i / Odim;            // local batch 0..31
        const unsigned short* hr = hbuf[0] + (b << 7);
        float s = bfc[o];
        const float* wr = wfc + o * Hdim;
        #pragma unroll 8
        for (int k2 = 0; k2 < Hdim; ++k2) {
            int idx = (((k2 >> 3) ^ (b & 15)) << 3) + (k2 & 7);   // unswizzle
            HS s2; s2.s = hr[idx];
            s = __builtin_fmaf(wr[k2], (float)s2.h, s);
        }
        int bg2 = half * BH + b;     // global batch
        out[(size_t)bg2 * Odim * Pdim + (size_t)o * Pdim + p] = s;
    }
}

extern "C" void kernel_launch(void* const* d_in, const int* in_sizes, int n_in,
                              void* d_out, int out_size, void* d_ws, size_t ws_size,
                              hipStream_t stream) {
    const float* x    = (const float*)d_in[0];
    const float* W_ih = (const float*)d_in[1];
    const float* W_hh = (const float*)d_in[2];
    const float* b_ih = (const float*)d_in[3];
    const float* b_hh = (const float*)d_in[4];
    const float* W_fc = (const float*)d_in[5];
    const float* b_fc = (const float*)d_in[6];
    float* out = (float*)d_out;

    lstm_fused<<<dim3(2 * Pdim), dim3(512), 0, stream>>>(x, W_ih, W_hh, b_ih, b_hh, W_fc, b_fc, out);
}